// Round 5
// baseline (521.056 us; speedup 1.0000x reference)
//
#include <hip/hip_runtime.h>
#include <stdint.h>

#define NB 2
#define NC 256
#define NH 96
#define NW 160
#define HP 98     // NH + 2 (1-pad for 3x3 convs)
#define WP 162    // NW + 2
#define CATC 768  // concat channels
#define P8H 112   // NH + 16 (8-pad for correlation)
#define P8W 176   // NW + 16

typedef __bf16 bf16x8 __attribute__((ext_vector_type(8)));
typedef float f32x4 __attribute__((ext_vector_type(4)));

static __device__ __forceinline__ uint16_t f2bf(float f) {
  uint32_t u = __float_as_uint(f);
  return (uint16_t)((u + 0x7fffu + ((u >> 16) & 1u)) >> 16);  // RNE
}

static __device__ __forceinline__ void gload16(const void* g, void* l) {
  __builtin_amdgcn_global_load_lds(
      (const __attribute__((address_space(1))) uint32_t*)g,
      (__attribute__((address_space(3))) uint32_t*)l, 16, 0, 0);
}

// ---------------- weight prep: W[co][ci][3][3] f32 -> [t*(ci/32)+cb][co][32] bf16 ----------------
__global__ void __launch_bounds__(256) wprep_kernel(const float* __restrict__ wsrc,
                                                    uint16_t* __restrict__ dst, int cin) {
  int co = blockIdx.x;
  int nb = cin >> 5;
  for (int ci = threadIdx.x; ci < cin; ci += 256) {
    const float* s = wsrc + ((size_t)co * cin + ci) * 9;
    int cb = ci >> 5, cil = ci & 31;
#pragma unroll
    for (int t = 0; t < 9; ++t) {
      dst[(((size_t)t * nb + cb) * 256 + co) * 32 + cil] = f2bf(s[t]);
    }
  }
}

// ---------------- NCHW f32 -> padded NHWC bf16 (fcat sections + f1p8) ----------------
__global__ void __launch_bounds__(256) transpose_kernel(const float* __restrict__ f0,
                                                        const float* __restrict__ f1,
                                                        uint16_t* __restrict__ fcat,
                                                        uint16_t* __restrict__ f1p8) {
  __shared__ float tile[32][33];
  int tid = threadIdx.x;
  int tx = tid & 31, ty = tid >> 5;
  int xb = blockIdx.x;        // 0..4  (32 x each)
  int y = blockIdx.y;         // 0..95
  int z = blockIdx.z;         // b(2) * which(2) * cb(8)
  int b = z >> 4, which = (z >> 3) & 1, cb = z & 7;
  const float* src = which ? f1 : f0;
  int x0 = xb * 32;
#pragma unroll
  for (int j = 0; j < 4; ++j) {
    int c = cb * 32 + ty + j * 8;
    tile[ty + j * 8][tx] = src[((size_t)(b * NC + c) * NH + y) * NW + x0 + tx];
  }
  __syncthreads();
#pragma unroll
  for (int j = 0; j < 4; ++j) {
    int lx = ty + j * 8;
    int x = x0 + lx;
    int c = cb * 32 + tx;
    uint16_t v = f2bf(tile[tx][lx]);
    size_t base = ((size_t)(b * HP + y + 1) * WP + (x + 1)) * CATC;
    if (which == 0) {
      fcat[base + c] = v;
    } else {
      fcat[base + 512 + c] = v;
      f1p8[((size_t)(b * P8H + y + 8) * P8W + (x + 8)) * NC + c] = v;
    }
  }
}

// ---------------- correlation via MFMA band-GEMM: writes fcat channels 256..511 ----------------
__global__ void __launch_bounds__(256) corr_kernel(const uint16_t* __restrict__ fcat,
                                                   const uint16_t* __restrict__ f1p8,
                                                   uint16_t* __restrict__ fout) {
  int tid = threadIdx.x;
  int lane = tid & 63, w = tid >> 6;
  int lr = lane & 15, lk = lane >> 4;
  int lin = blockIdx.x;                       // 0..959
  int wid = (lin & 7) * 120 + (lin >> 3);     // XCD swizzle: y-contiguous chunks per XCD
  int y = wid % 96, xt = wid / 96;
  int b = blockIdx.y;
  int x0 = xt * 16;

  bf16x8 af[8];
  const uint16_t* abase = fcat + ((size_t)(b * HP + y + 1) * WP + (x0 + lr + 1)) * CATC + lk * 8;
#pragma unroll
  for (int kk = 0; kk < 8; ++kk) af[kk] = *(const bf16x8*)(abase + kk * 32);

  for (int g = 0; g < 4; ++g) {
    int pi = g * 4 + w;
    const uint16_t* bbase =
        f1p8 + ((size_t)(b * P8H + y + pi) * P8W + x0) * NC + lk * 8;
    bf16x8 bf0[8], bf1[8];
#pragma unroll
    for (int kk = 0; kk < 8; ++kk) {
      bf0[kk] = *(const bf16x8*)(bbase + (size_t)lr * NC + kk * 32);
      bf1[kk] = *(const bf16x8*)(bbase + (size_t)(16 + lr) * NC + kk * 32);
    }
    f32x4 acc0 = (f32x4){0.f, 0.f, 0.f, 0.f};
    f32x4 acc1 = (f32x4){0.f, 0.f, 0.f, 0.f};
#pragma unroll
    for (int kk = 0; kk < 8; ++kk) {
      acc0 = __builtin_amdgcn_mfma_f32_16x16x32_bf16(af[kk], bf0[kk], acc0, 0, 0, 0);
      acc1 = __builtin_amdgcn_mfma_f32_16x16x32_bf16(af[kk], bf1[kk], acc1, 0, 0, 0);
    }
    size_t orow = ((size_t)(b * HP + y + 1) * WP + (x0 + 1)) * CATC + 256 + (size_t)pi * 16;
#pragma unroll
    for (int j = 0; j < 4; ++j) {
      int xl = lk * 4 + j;
      int pj0 = lr - xl;
      if (pj0 >= 0) fout[orow + (size_t)xl * CATC + pj0] = f2bf(acc0[j]);
      int pj1 = 16 + lr - xl;
      if (pj1 < 16) fout[orow + (size_t)xl * CATC + pj1] = f2bf(acc1[j]);
    }
  }
}

// ---------------- conv1: pipelined implicit GEMM ----------------
// BM=128 px (16x x 8y), BN=256 co, BK=32, 8 waves. A (fcat) triple-buffered in LDS via
// global_load_lds; B (weights, L2-resident) global->reg with 1-step prefetch.
// CRITICAL ORDER: register B-loads are issued BEFORE the LDS stage each iteration, so the
// compiler's wait on B(kt+1) (before the bcur=bnext use) drains only the OLDER stage(kt+1)
// — the exact fence the barrier needs — while stage(kt+2) stays in flight. vmcnt(1) backstop.
__global__ __launch_bounds__(512, 2) void conv1_kernel(const uint16_t* __restrict__ fcat,
                                                       const uint16_t* __restrict__ wp,
                                                       const float* __restrict__ bias,
                                                       uint16_t* __restrict__ hbuf) {
  constexpr int CBS = 24, NT = 9 * CBS;  // 216 K-steps
  __shared__ __align__(16) uint16_t As[3][128 * 32];  // 3 x 8 KB
  int tid = threadIdx.x;
  int w = tid >> 6, lane = tid & 63;
  int lr = lane & 15, lk = lane >> 4;
  int wr = w >> 2, wc = w & 3;  // px-half, co-quarter

  int orig = blockIdx.x;                     // 0..239
  int swz = (orig & 7) * 30 + (orig >> 3);   // XCD-bijective (240 % 8 == 0)
  int b = swz / 120, rem = swz % 120;
  int xt = rem / 12, yt = rem % 12;
  int x0 = xt * 16, y0 = yt * 8;

  // A staging: wave w stages px-rows w*16..w*16+15; lane l -> row w*16+(l>>2), chunk l&3
  int sr = w * 16 + (lane >> 2);
  int scp = lane & 3;
  int sy = y0 + (sr >> 4), sx = x0 + (sr & 15);
  uint16_t* lds0 = &As[0][0] + sr * 32 + scp * 8;  // == wave base + lane*16B (linear)

  float bv[4];
#pragma unroll
  for (int n = 0; n < 4; ++n) bv[n] = bias[wc * 64 + n * 16 + lr];

  f32x4 acc[4][4];
#pragma unroll
  for (int m = 0; m < 4; ++m)
#pragma unroll
    for (int n = 0; n < 4; ++n) acc[m][n] = (f32x4){0.f, 0.f, 0.f, 0.f};

#define STAGE1(kt, buf)                                                                   \
  {                                                                                       \
    int t_ = (kt) / CBS, cb_ = (kt) - t_ * CBS;                                           \
    int dy_ = t_ / 3, dx_ = t_ - dy_ * 3;                                                 \
    const uint16_t* g_ =                                                                  \
        fcat + ((size_t)(b * HP + sy + dy_) * WP + (sx + dx_)) * CATC + cb_ * 32 + scp * 8; \
    gload16(g_, lds0 + (buf)*4096);                                                       \
  }

#define LOADB1(dst, kt)                                                       \
  {                                                                           \
    const uint16_t* s_ = wp + ((size_t)(kt)*256 + wc * 64 + lr) * 32 + lk * 8; \
    _Pragma("unroll") for (int n_ = 0; n_ < 4; ++n_) dst[n_] =                \
        *(const bf16x8*)(s_ + (size_t)n_ * 16 * 32);                          \
  }

  bf16x8 bcur[4], bnext[4];
  LOADB1(bcur, 0);          // B first (older than stages)
  STAGE1(0, 0);
  STAGE1(1, 1);
  asm volatile("s_waitcnt vmcnt(1)" ::: "memory");  // B0+stage0 done; stage1 in flight
  __builtin_amdgcn_s_barrier();

  for (int kt = 0; kt < NT; ++kt) {
    int bkt = kt + 1 < NT ? kt + 1 : NT - 1;
    LOADB1(bnext, bkt);                       // issued BEFORE the stage
    int nkt = kt + 2 < NT ? kt + 2 : NT - 1;  // clamped tail -> unread buffer, uniform count
    STAGE1(nkt, (kt + 2) % 3);
    const uint16_t* a = &As[kt % 3][0];
    bf16x8 af[4];
#pragma unroll
    for (int m = 0; m < 4; ++m)
      af[m] = *(const bf16x8*)(a + (wr * 64 + m * 16 + lr) * 32 + lk * 8);
#pragma unroll
    for (int m = 0; m < 4; ++m)
#pragma unroll
      for (int n = 0; n < 4; ++n)
        acc[m][n] = __builtin_amdgcn_mfma_f32_16x16x32_bf16(af[m], bcur[n], acc[m][n], 0, 0, 0);
#pragma unroll
    for (int n = 0; n < 4; ++n) bcur[n] = bnext[n];
    // allow only stage(kt+2) in flight: forces stage(kt+1)+B(kt+1) retired before barrier
    asm volatile("s_waitcnt vmcnt(1)" ::: "memory");
    __builtin_amdgcn_s_barrier();
  }

  // epilogue: D col = co (lane&15), row = px ((lane>>4)*4+j); relu -> hbuf NHWC-pad bf16
#pragma unroll
  for (int m = 0; m < 4; ++m) {
#pragma unroll
    for (int j = 0; j < 4; ++j) {
      int px = wr * 64 + m * 16 + lk * 4 + j;
      int py = px >> 4, pxx = px & 15;
      size_t base = ((size_t)(b * HP + y0 + py + 1) * WP + (x0 + pxx + 1)) * NC;
#pragma unroll
      for (int n = 0; n < 4; ++n) {
        float v = acc[m][n][j] + bv[n];
        v = v > 0.f ? v : 0.f;
        hbuf[base + wc * 64 + n * 16 + lr] = f2bf(v);
      }
    }
  }
#undef STAGE1
#undef LOADB1
}

// ---------------- conv2: same pipeline, operands swapped ----------------
// A = weights [256 co][32] in LDS (triple-buffered, gload_lds, 2 ops/stage); B = activations
// (hbuf) global->reg 1-step prefetch, issued BEFORE the stage. vmcnt(2) backstop.
__global__ __launch_bounds__(512, 2) void conv2_kernel(const uint16_t* __restrict__ hbuf,
                                                       const uint16_t* __restrict__ wp,
                                                       const float* __restrict__ bias,
                                                       const float* __restrict__ f1,
                                                       float* __restrict__ out) {
  constexpr int CBS = 8, NT = 72;
  __shared__ __align__(16) uint16_t Ws[3][256 * 32];  // 3 x 16 KB
  int tid = threadIdx.x;
  int w = tid >> 6, lane = tid & 63;
  int lr = lane & 15, lk = lane >> 4;
  int wq = w & 3;    // co quarter (M)
  int wph = w >> 2;  // px half (N)

  int orig = blockIdx.x;
  int swz = (orig & 7) * 30 + (orig >> 3);
  int b = swz / 120, rem = swz % 120;
  int xt = rem / 12, yt = rem % 12;
  int x0 = xt * 16, y0 = yt * 8;

  int scp = lane & 3;

  float bv[4][4];
#pragma unroll
  for (int m = 0; m < 4; ++m)
#pragma unroll
    for (int j = 0; j < 4; ++j) bv[m][j] = bias[wq * 64 + m * 16 + lk * 4 + j];

  f32x4 acc[4][4];
#pragma unroll
  for (int m = 0; m < 4; ++m)
#pragma unroll
    for (int n = 0; n < 4; ++n) acc[m][n] = (f32x4){0.f, 0.f, 0.f, 0.f};

#define STAGE2(kt, buf)                                                        \
  {                                                                            \
    const uint16_t* g_ = wp + ((size_t)(kt)*256) * 32;                         \
    _Pragma("unroll") for (int j_ = 0; j_ < 2; ++j_) {                         \
      int r_ = w * 32 + j_ * 16 + (lane >> 2);                                 \
      gload16(g_ + r_ * 32 + scp * 8, &Ws[buf][0] + r_ * 32 + scp * 8);        \
    }                                                                          \
  }

#define LOADX2(dst, kt)                                                                     \
  {                                                                                         \
    int t_ = (kt) >> 3, cb_ = (kt)&7;                                                       \
    int dy_ = t_ / 3, dx_ = t_ - dy_ * 3;                                                   \
    _Pragma("unroll") for (int n_ = 0; n_ < 4; ++n_) {                                      \
      const uint16_t* g_ = hbuf +                                                           \
          ((size_t)(b * HP + y0 + wph * 4 + n_ + dy_) * WP + (x0 + lr + dx_)) * NC +        \
          cb_ * 32 + lk * 8;                                                                \
      dst[n_] = *(const bf16x8*)g_;                                                         \
    }                                                                                       \
  }

  bf16x8 xcur[4], xnext[4];
  LOADX2(xcur, 0);          // X first (older than stages)
  STAGE2(0, 0);
  STAGE2(1, 1);
  asm volatile("s_waitcnt vmcnt(2)" ::: "memory");  // X0+stage0 done; stage1 (2 ops) in flight
  __builtin_amdgcn_s_barrier();

  for (int kt = 0; kt < NT; ++kt) {
    int bkt = kt + 1 < NT ? kt + 1 : NT - 1;
    LOADX2(xnext, bkt);                       // issued BEFORE the stage
    int nkt = kt + 2 < NT ? kt + 2 : NT - 1;
    STAGE2(nkt, (kt + 2) % 3);
    const uint16_t* a = &Ws[kt % 3][0];
    bf16x8 af[4];
#pragma unroll
    for (int m = 0; m < 4; ++m)
      af[m] = *(const bf16x8*)(a + (wq * 64 + m * 16 + lr) * 32 + lk * 8);
#pragma unroll
    for (int m = 0; m < 4; ++m)
#pragma unroll
      for (int n = 0; n < 4; ++n)
        acc[m][n] = __builtin_amdgcn_mfma_f32_16x16x32_bf16(af[m], xcur[n], acc[m][n], 0, 0, 0);
#pragma unroll
    for (int n = 0; n < 4; ++n) xcur[n] = xnext[n];
    // allow only stage(kt+2) (2 ops) in flight: stage(kt+1)+X(kt+1) retired before barrier
    asm volatile("s_waitcnt vmcnt(2)" ::: "memory");
    __builtin_amdgcn_s_barrier();
  }

  // epilogue: row = co = wq*64+m*16+lk*4+j, col = px -> (py = wph*4+n, pxx = lr); f32 NCHW
#pragma unroll
  for (int m = 0; m < 4; ++m) {
#pragma unroll
    for (int j = 0; j < 4; ++j) {
      int co = wq * 64 + m * 16 + lk * 4 + j;
#pragma unroll
      for (int n = 0; n < 4; ++n) {
        int y = y0 + wph * 4 + n;
        size_t idx = ((size_t)(b * NC + co) * NH + y) * NW + x0 + lr;
        out[idx] = acc[m][n][j] + bv[m][j] + f1[idx];
      }
    }
  }
#undef STAGE2
#undef LOADX2
}

extern "C" void kernel_launch(void* const* d_in, const int* in_sizes, int n_in,
                              void* d_out, int out_size, void* d_ws, size_t ws_size,
                              hipStream_t stream) {
  (void)in_sizes; (void)n_in; (void)out_size; (void)ws_size;
  const float* f0 = (const float*)d_in[0];
  const float* f1 = (const float*)d_in[1];
  const float* W1 = (const float*)d_in[2];
  const float* b1 = (const float*)d_in[3];
  const float* W2 = (const float*)d_in[4];
  const float* b2 = (const float*)d_in[5];
  float* out = (float*)d_out;

  char* ws = (char*)d_ws;
  size_t s_fcat = (size_t)NB * HP * WP * CATC * 2;  // 48.8 MB
  size_t s_f1p8 = (size_t)NB * P8H * P8W * NC * 2;  // 20.2 MB
  size_t s_h = (size_t)NB * HP * WP * NC * 2;       // 16.3 MB
  size_t s_bp1 = (size_t)9 * 24 * 256 * 32 * 2;     // 3.5 MB
  uint16_t* fcat = (uint16_t*)ws;
  uint16_t* f1p8 = (uint16_t*)(ws + s_fcat);
  uint16_t* hbuf = (uint16_t*)(ws + s_fcat + s_f1p8);
  uint16_t* bp1 = (uint16_t*)(ws + s_fcat + s_f1p8 + s_h);
  uint16_t* bp2 = (uint16_t*)(ws + s_fcat + s_f1p8 + s_h + s_bp1);

  hipMemsetAsync(fcat, 0, s_fcat, stream);
  hipMemsetAsync(f1p8, 0, s_f1p8, stream);
  hipMemsetAsync(hbuf, 0, s_h, stream);

  wprep_kernel<<<256, 256, 0, stream>>>(W1, bp1, 768);
  wprep_kernel<<<256, 256, 0, stream>>>(W2, bp2, 256);
  transpose_kernel<<<dim3(5, 96, 32), 256, 0, stream>>>(f0, f1, fcat, f1p8);
  corr_kernel<<<dim3(960, 2), 256, 0, stream>>>(fcat, f1p8, fcat);
  conv1_kernel<<<240, 512, 0, stream>>>(fcat, bp1, b1, hbuf);
  conv2_kernel<<<240, 512, 0, stream>>>(hbuf, bp2, b2, f1, out);
}

// Round 7
// 427.534 us; speedup vs baseline: 1.2187x; 1.2187x over previous
//
#include <hip/hip_runtime.h>
#include <stdint.h>

#define NB 2
#define NC 256
#define NH 96
#define NW 160
#define HP 98     // NH + 2 (1-pad for 3x3 convs)
#define WP 162    // NW + 2
#define CATC 768  // concat channels
#define P8H 112   // NH + 16 (8-pad for correlation)
#define P8W 176   // NW + 16

typedef __bf16 bf16x8 __attribute__((ext_vector_type(8)));
typedef float f32x4 __attribute__((ext_vector_type(4)));

static __device__ __forceinline__ uint16_t f2bf(float f) {
  uint32_t u = __float_as_uint(f);
  return (uint16_t)((u + 0x7fffu + ((u >> 16) & 1u)) >> 16);  // RNE
}

static __device__ __forceinline__ void gload16(const void* g, void* l) {
  __builtin_amdgcn_global_load_lds(
      (const __attribute__((address_space(1))) uint32_t*)g,
      (__attribute__((address_space(3))) uint32_t*)l, 16, 0, 0);
}

// ---------------- weight prep: W[co][ci][3][3] f32 -> [t*(ci/32)+cb][co][32] bf16 ----------------
__global__ void __launch_bounds__(256) wprep_kernel(const float* __restrict__ wsrc,
                                                    uint16_t* __restrict__ dst, int cin) {
  int co = blockIdx.x;
  int nb = cin >> 5;
  for (int ci = threadIdx.x; ci < cin; ci += 256) {
    const float* s = wsrc + ((size_t)co * cin + ci) * 9;
    int cb = ci >> 5, cil = ci & 31;
#pragma unroll
    for (int t = 0; t < 9; ++t) {
      dst[(((size_t)t * nb + cb) * 256 + co) * 32 + cil] = f2bf(s[t]);
    }
  }
}

// ---------------- NCHW f32 -> padded NHWC bf16 (fcat sections + f1p8) ----------------
__global__ void __launch_bounds__(256) transpose_kernel(const float* __restrict__ f0,
                                                        const float* __restrict__ f1,
                                                        uint16_t* __restrict__ fcat,
                                                        uint16_t* __restrict__ f1p8) {
  __shared__ float tile[32][33];
  int tid = threadIdx.x;
  int tx = tid & 31, ty = tid >> 5;
  int xb = blockIdx.x;        // 0..4  (32 x each)
  int y = blockIdx.y;         // 0..95
  int z = blockIdx.z;         // b(2) * which(2) * cb(8)
  int b = z >> 4, which = (z >> 3) & 1, cb = z & 7;
  const float* src = which ? f1 : f0;
  int x0 = xb * 32;
#pragma unroll
  for (int j = 0; j < 4; ++j) {
    int c = cb * 32 + ty + j * 8;
    tile[ty + j * 8][tx] = src[((size_t)(b * NC + c) * NH + y) * NW + x0 + tx];
  }
  __syncthreads();
#pragma unroll
  for (int j = 0; j < 4; ++j) {
    int lx = ty + j * 8;
    int x = x0 + lx;
    int c = cb * 32 + tx;
    uint16_t v = f2bf(tile[tx][lx]);
    size_t base = ((size_t)(b * HP + y + 1) * WP + (x + 1)) * CATC;
    if (which == 0) {
      fcat[base + c] = v;
    } else {
      fcat[base + 512 + c] = v;
      f1p8[((size_t)(b * P8H + y + 8) * P8W + (x + 8)) * NC + c] = v;
    }
  }
}

// ---------------- correlation via MFMA band-GEMM: writes fcat channels 256..511 ----------------
__global__ void __launch_bounds__(256) corr_kernel(const uint16_t* __restrict__ fcat,
                                                   const uint16_t* __restrict__ f1p8,
                                                   uint16_t* __restrict__ fout) {
  int tid = threadIdx.x;
  int lane = tid & 63, w = tid >> 6;
  int lr = lane & 15, lk = lane >> 4;
  int lin = blockIdx.x;                       // 0..959
  int wid = (lin & 7) * 120 + (lin >> 3);     // XCD swizzle: y-contiguous chunks per XCD
  int y = wid % 96, xt = wid / 96;
  int b = blockIdx.y;
  int x0 = xt * 16;

  bf16x8 af[8];
  const uint16_t* abase = fcat + ((size_t)(b * HP + y + 1) * WP + (x0 + lr + 1)) * CATC + lk * 8;
#pragma unroll
  for (int kk = 0; kk < 8; ++kk) af[kk] = *(const bf16x8*)(abase + kk * 32);

  for (int g = 0; g < 4; ++g) {
    int pi = g * 4 + w;
    const uint16_t* bbase =
        f1p8 + ((size_t)(b * P8H + y + pi) * P8W + x0) * NC + lk * 8;
    bf16x8 bf0[8], bf1[8];
#pragma unroll
    for (int kk = 0; kk < 8; ++kk) {
      bf0[kk] = *(const bf16x8*)(bbase + (size_t)lr * NC + kk * 32);
      bf1[kk] = *(const bf16x8*)(bbase + (size_t)(16 + lr) * NC + kk * 32);
    }
    f32x4 acc0 = (f32x4){0.f, 0.f, 0.f, 0.f};
    f32x4 acc1 = (f32x4){0.f, 0.f, 0.f, 0.f};
#pragma unroll
    for (int kk = 0; kk < 8; ++kk) {
      acc0 = __builtin_amdgcn_mfma_f32_16x16x32_bf16(af[kk], bf0[kk], acc0, 0, 0, 0);
      acc1 = __builtin_amdgcn_mfma_f32_16x16x32_bf16(af[kk], bf1[kk], acc1, 0, 0, 0);
    }
    size_t orow = ((size_t)(b * HP + y + 1) * WP + (x0 + 1)) * CATC + 256 + (size_t)pi * 16;
#pragma unroll
    for (int j = 0; j < 4; ++j) {
      int xl = lk * 4 + j;
      int pj0 = lr - xl;
      if (pj0 >= 0) fout[orow + (size_t)xl * CATC + pj0] = f2bf(acc0[j]);
      int pj1 = 16 + lr - xl;
      if (pj1 < 16) fout[orow + (size_t)xl * CATC + pj1] = f2bf(acc1[j]);
    }
  }
}

// ---------------- conv1: pipelined implicit GEMM, unroll-2 ----------------
// BM=128 px, BN=256 co, BK=32, 8 waves. A (fcat) 3-buffered LDS via global_load_lds with
// bank-swizzle (chunk ^= (row>>1)&3, applied on SOURCE addr + read offset; LDS dest linear).
// B (weights) in 2 register buffers b0/b1: loaded in sub-iter kt, first used kt+2 (>=1 full
// step of slack). Pre-barrier vmcnt(5) == current region's op count -> drains all PRIOR
// regions (stage kt+1 guaranteed landed) independent of intra-region scheduling order.
__global__ __launch_bounds__(512, 2) void conv1_kernel(const uint16_t* __restrict__ fcat,
                                                       const uint16_t* __restrict__ wp,
                                                       const float* __restrict__ bias,
                                                       uint16_t* __restrict__ hbuf) {
  constexpr int CBS = 24, NT = 9 * CBS;  // 216 K-steps (even)
  __shared__ __align__(16) uint16_t As[3][128 * 32];  // 3 x 8 KB
  int tid = threadIdx.x;
  int w = tid >> 6, lane = tid & 63;
  int lr = lane & 15, lk = lane >> 4;
  int wr = w >> 2, wc = w & 3;  // px-half, co-quarter

  int orig = blockIdx.x;                     // 0..239
  int swz = (orig & 7) * 30 + (orig >> 3);   // XCD-bijective (240 % 8 == 0)
  int b = swz / 120, rem = swz % 120;
  int xt = rem / 12, yt = rem % 12;
  int x0 = xt * 16, y0 = yt * 8;

  // A staging: wave w stages px-rows w*16..w*16+15; lane l -> row w*16+(l>>2), slot l&3
  int sr = w * 16 + (lane >> 2);
  int scp = lane & 3;
  int cg = scp ^ ((sr >> 1) & 3);  // swizzled global chunk for this lane's linear LDS slot
  int sy = y0 + (sr >> 4), sx = x0 + (sr & 15);
  uint16_t* lds0 = &As[0][0] + sr * 32 + scp * 8;  // linear: wave base + lane*16B
  int cswz = (lk ^ ((lr >> 1) & 3)) * 8;           // read-side swizzled chunk offset (elems)

  float bv[4];
#pragma unroll
  for (int n = 0; n < 4; ++n) bv[n] = bias[wc * 64 + n * 16 + lr];

  f32x4 acc[4][4];
#pragma unroll
  for (int m = 0; m < 4; ++m)
#pragma unroll
    for (int n = 0; n < 4; ++n) acc[m][n] = (f32x4){0.f, 0.f, 0.f, 0.f};

#define STAGE1(kt, buf)                                                                     \
  {                                                                                         \
    int t_ = (kt) / CBS, cb_ = (kt) - t_ * CBS;                                             \
    int dy_ = t_ / 3, dx_ = t_ - dy_ * 3;                                                   \
    const uint16_t* g_ =                                                                    \
        fcat + ((size_t)(b * HP + sy + dy_) * WP + (sx + dx_)) * CATC + cb_ * 32 + cg * 8;  \
    gload16(g_, lds0 + (buf)*4096);                                                         \
  }

#define LOADB1(dst, kt)                                                        \
  {                                                                            \
    const uint16_t* s_ = wp + ((size_t)(kt)*256 + wc * 64 + lr) * 32 + lk * 8; \
    _Pragma("unroll") for (int n_ = 0; n_ < 4; ++n_) dst[n_] =                 \
        *(const bf16x8*)(s_ + (size_t)n_ * 512);                               \
  }

#define MFMA1(bufidx, breg)                                                          \
  {                                                                                  \
    const uint16_t* a_ = &As[bufidx][0];                                             \
    bf16x8 af[4];                                                                    \
    _Pragma("unroll") for (int m_ = 0; m_ < 4; ++m_) af[m_] =                        \
        *(const bf16x8*)(a_ + (wr * 64 + m_ * 16 + lr) * 32 + cswz);                 \
    _Pragma("unroll") for (int m_ = 0; m_ < 4; ++m_)                                 \
        _Pragma("unroll") for (int n_ = 0; n_ < 4; ++n_) acc[m_][n_] =               \
            __builtin_amdgcn_mfma_f32_16x16x32_bf16(af[m_], breg[n_], acc[m_][n_],   \
                                                    0, 0, 0);                        \
  }

  bf16x8 b0[4], b1[4];
  STAGE1(0, 0);
  LOADB1(b0, 0);
  STAGE1(1, 1);
  LOADB1(b1, 1);
  asm volatile("s_waitcnt vmcnt(0)" ::: "memory");  // once: everything landed
  __builtin_amdgcn_s_barrier();

  for (int kt = 0; kt < NT; kt += 2) {
    {  // even sub-iter: buffer kt%3, B-regs b0
      MFMA1(kt % 3, b0);
      int nk = (kt + 2 < NT) ? kt + 2 : NT - 1;
      STAGE1(nk, (kt + 2) % 3);
      LOADB1(b0, nk);  // first used at kt+2
      asm volatile("s_waitcnt vmcnt(5)" ::: "memory");  // drain all prior regions
      __builtin_amdgcn_s_barrier();
    }
    {  // odd sub-iter: buffer (kt+1)%3, B-regs b1
      MFMA1((kt + 1) % 3, b1);
      int nk = (kt + 3 < NT) ? kt + 3 : NT - 1;
      STAGE1(nk, (kt + 3) % 3);
      LOADB1(b1, nk);  // first used at kt+3
      asm volatile("s_waitcnt vmcnt(5)" ::: "memory");
      __builtin_amdgcn_s_barrier();
    }
  }

  // epilogue: D col = co (lane&15), row = px ((lane>>4)*4+j); relu -> hbuf NHWC-pad bf16
#pragma unroll
  for (int m = 0; m < 4; ++m) {
#pragma unroll
    for (int j = 0; j < 4; ++j) {
      int px = wr * 64 + m * 16 + lk * 4 + j;
      int py = px >> 4, pxx = px & 15;
      size_t base = ((size_t)(b * HP + y0 + py + 1) * WP + (x0 + pxx + 1)) * NC;
#pragma unroll
      for (int n = 0; n < 4; ++n) {
        float v = acc[m][n][j] + bv[n];
        v = v > 0.f ? v : 0.f;
        hbuf[base + wc * 64 + n * 16 + lr] = f2bf(v);
      }
    }
  }
#undef STAGE1
#undef LOADB1
#undef MFMA1
}

// ---------------- conv2: same unroll-2 pipeline, operands swapped ----------------
// A = weights [256 co][32] in 3-buffer LDS (gload_lds, 2 ops/stage, same bank swizzle);
// B = activations (hbuf) in 2 register buffers (loaded kt, used kt+2). vmcnt(6) per barrier.
__global__ __launch_bounds__(512, 2) void conv2_kernel(const uint16_t* __restrict__ hbuf,
                                                       const uint16_t* __restrict__ wp,
                                                       const float* __restrict__ bias,
                                                       const float* __restrict__ f1,
                                                       float* __restrict__ out) {
  constexpr int NT = 72;  // even
  __shared__ __align__(16) uint16_t Ws[3][256 * 32];  // 3 x 16 KB
  int tid = threadIdx.x;
  int w = tid >> 6, lane = tid & 63;
  int lr = lane & 15, lk = lane >> 4;
  int wq = w & 3;    // co quarter (M)
  int wph = w >> 2;  // px half (N)

  int orig = blockIdx.x;
  int swz = (orig & 7) * 30 + (orig >> 3);
  int b = swz / 120, rem = swz % 120;
  int xt = rem / 12, yt = rem % 12;
  int x0 = xt * 16, y0 = yt * 8;

  int scp = lane & 3;
  int srw0 = w * 32 + (lane >> 2);  // staged row, j_=0 (j_=1 adds 16)
  int cswz = (lk ^ ((lr >> 1) & 3)) * 8;

  float bv[4][4];
#pragma unroll
  for (int m = 0; m < 4; ++m)
#pragma unroll
    for (int j = 0; j < 4; ++j) bv[m][j] = bias[wq * 64 + m * 16 + lk * 4 + j];

  f32x4 acc[4][4];
#pragma unroll
  for (int m = 0; m < 4; ++m)
#pragma unroll
    for (int n = 0; n < 4; ++n) acc[m][n] = (f32x4){0.f, 0.f, 0.f, 0.f};

#define STAGE2(kt, buf)                                                         \
  {                                                                             \
    const uint16_t* g_ = wp + ((size_t)(kt)*256) * 32;                          \
    _Pragma("unroll") for (int j_ = 0; j_ < 2; ++j_) {                          \
      int r_ = srw0 + j_ * 16;                                                  \
      int cg_ = scp ^ ((r_ >> 1) & 3);                                          \
      gload16(g_ + (size_t)r_ * 32 + cg_ * 8,                                   \
              &Ws[buf][0] + r_ * 32 + scp * 8);                                 \
    }                                                                           \
  }

#define LOADX2(dst, kt)                                                                     \
  {                                                                                         \
    int t_ = (kt) >> 3, cb_ = (kt)&7;                                                       \
    int dy_ = t_ / 3, dx_ = t_ - dy_ * 3;                                                   \
    _Pragma("unroll") for (int n_ = 0; n_ < 4; ++n_) {                                      \
      const uint16_t* g_ = hbuf +                                                           \
          ((size_t)(b * HP + y0 + wph * 4 + n_ + dy_) * WP + (x0 + lr + dx_)) * NC +        \
          cb_ * 32 + lk * 8;                                                                \
      dst[n_] = *(const bf16x8*)g_;                                                         \
    }                                                                                       \
  }

#define MFMA2(bufidx, xreg)                                                          \
  {                                                                                  \
    const uint16_t* a_ = &Ws[bufidx][0];                                             \
    bf16x8 aw[4];                                                                    \
    _Pragma("unroll") for (int m_ = 0; m_ < 4; ++m_) aw[m_] =                        \
        *(const bf16x8*)(a_ + (wq * 64 + m_ * 16 + lr) * 32 + cswz);                 \
    _Pragma("unroll") for (int m_ = 0; m_ < 4; ++m_)                                 \
        _Pragma("unroll") for (int n_ = 0; n_ < 4; ++n_) acc[m_][n_] =               \
            __builtin_amdgcn_mfma_f32_16x16x32_bf16(aw[m_], xreg[n_], acc[m_][n_],   \
                                                    0, 0, 0);                        \
  }

  bf16x8 x0r[4], x1r[4];
  STAGE2(0, 0);
  LOADX2(x0r, 0);
  STAGE2(1, 1);
  LOADX2(x1r, 1);
  asm volatile("s_waitcnt vmcnt(0)" ::: "memory");
  __builtin_amdgcn_s_barrier();

  for (int kt = 0; kt < NT; kt += 2) {
    {
      MFMA2(kt % 3, x0r);
      int nk = (kt + 2 < NT) ? kt + 2 : NT - 1;
      STAGE2(nk, (kt + 2) % 3);
      LOADX2(x0r, nk);
      asm volatile("s_waitcnt vmcnt(6)" ::: "memory");  // drain all prior regions
      __builtin_amdgcn_s_barrier();
    }
    {
      MFMA2((kt + 1) % 3, x1r);
      int nk = (kt + 3 < NT) ? kt + 3 : NT - 1;
      STAGE2(nk, (kt + 3) % 3);
      LOADX2(x1r, nk);
      asm volatile("s_waitcnt vmcnt(6)" ::: "memory");
      __builtin_amdgcn_s_barrier();
    }
  }

  // epilogue: row = co = wq*64+m*16+lk*4+j, col = px -> (py = wph*4+n, pxx = lr); f32 NCHW
#pragma unroll
  for (int m = 0; m < 4; ++m) {
#pragma unroll
    for (int j = 0; j < 4; ++j) {
      int co = wq * 64 + m * 16 + lk * 4 + j;
#pragma unroll
      for (int n = 0; n < 4; ++n) {
        int y = y0 + wph * 4 + n;
        size_t idx = ((size_t)(b * NC + co) * NH + y) * NW + x0 + lr;
        out[idx] = acc[m][n][j] + bv[m][j] + f1[idx];
      }
    }
  }
#undef STAGE2
#undef LOADX2
#undef MFMA2
}

extern "C" void kernel_launch(void* const* d_in, const int* in_sizes, int n_in,
                              void* d_out, int out_size, void* d_ws, size_t ws_size,
                              hipStream_t stream) {
  (void)in_sizes; (void)n_in; (void)out_size; (void)ws_size;
  const float* f0 = (const float*)d_in[0];
  const float* f1 = (const float*)d_in[1];
  const float* W1 = (const float*)d_in[2];
  const float* b1 = (const float*)d_in[3];
  const float* W2 = (const float*)d_in[4];
  const float* b2 = (const float*)d_in[5];
  float* out = (float*)d_out;

  char* ws = (char*)d_ws;
  size_t s_fcat = (size_t)NB * HP * WP * CATC * 2;  // 48.8 MB
  size_t s_f1p8 = (size_t)NB * P8H * P8W * NC * 2;  // 20.2 MB
  size_t s_h = (size_t)NB * HP * WP * NC * 2;       // 16.3 MB
  size_t s_bp1 = (size_t)9 * 24 * 256 * 32 * 2;     // 3.5 MB
  uint16_t* fcat = (uint16_t*)ws;
  uint16_t* f1p8 = (uint16_t*)(ws + s_fcat);
  uint16_t* hbuf = (uint16_t*)(ws + s_fcat + s_f1p8);
  uint16_t* bp1 = (uint16_t*)(ws + s_fcat + s_f1p8 + s_h);
  uint16_t* bp2 = (uint16_t*)(ws + s_fcat + s_f1p8 + s_h + s_bp1);

  hipMemsetAsync(fcat, 0, s_fcat, stream);
  hipMemsetAsync(f1p8, 0, s_f1p8, stream);
  hipMemsetAsync(hbuf, 0, s_h, stream);

  wprep_kernel<<<256, 256, 0, stream>>>(W1, bp1, 768);
  wprep_kernel<<<256, 256, 0, stream>>>(W2, bp2, 256);
  transpose_kernel<<<dim3(5, 96, 32), 256, 0, stream>>>(f0, f1, fcat, f1p8);
  corr_kernel<<<dim3(960, 2), 256, 0, stream>>>(fcat, f1p8, fcat);
  conv1_kernel<<<240, 512, 0, stream>>>(fcat, bp1, b1, hbuf);
  conv2_kernel<<<240, 512, 0, stream>>>(hbuf, bp2, b2, f1, out);
}

// Round 8
// 357.717 us; speedup vs baseline: 1.4566x; 1.1952x over previous
//
#include <hip/hip_runtime.h>
#include <stdint.h>

#define NB 2
#define NC 256
#define NH 96
#define NW 160
#define HP 98     // NH + 2 (1-pad for 3x3 convs)
#define WP 162    // NW + 2
#define CATC 768  // concat channels
#define P8H 112   // NH + 16 (8-pad for correlation)
#define P8W 176   // NW + 16

typedef __bf16 bf16x8 __attribute__((ext_vector_type(8)));
typedef float f32x4 __attribute__((ext_vector_type(4)));

static __device__ __forceinline__ uint16_t f2bf(float f) {
  uint32_t u = __float_as_uint(f);
  return (uint16_t)((u + 0x7fffu + ((u >> 16) & 1u)) >> 16);  // RNE
}

// ---------------- border zeroing (replaces 85 MB of full-buffer memsets) ----------------
__global__ void __launch_bounds__(256) bzero_kernel(uint16_t* __restrict__ fcat,
                                                    uint16_t* __restrict__ f1p8,
                                                    uint16_t* __restrict__ hbuf) {
  const uint4 z = {0u, 0u, 0u, 0u};
  int which = blockIdx.y, r = blockIdx.x, tid = threadIdx.x;
  if (which != 1) {
    if (r >= 2 * HP) return;
    int b = r / HP, y = r % HP;
    int C = which == 0 ? CATC : NC;
    uint16_t* buf = which == 0 ? fcat : hbuf;
    uint16_t* row = buf + (size_t)(b * HP + y) * WP * C;
    if (y == 0 || y == HP - 1) {
      int n8 = WP * C / 8;
      for (int i = tid; i < n8; i += 256) ((uint4*)row)[i] = z;
    } else {
      int n8 = C / 8;
      for (int i = tid; i < n8; i += 256) {
        ((uint4*)row)[i] = z;
        ((uint4*)(row + (size_t)(WP - 1) * C))[i] = z;
      }
    }
  } else {
    if (r >= 2 * P8H) return;
    int b = r / P8H, y = r % P8H;
    uint16_t* row = f1p8 + (size_t)(b * P8H + y) * P8W * NC;
    if (y < 8 || y >= P8H - 8) {
      int n8 = P8W * NC / 8;
      for (int i = tid; i < n8; i += 256) ((uint4*)row)[i] = z;
    } else {
      int n8 = 8 * NC / 8;
      for (int i = tid; i < n8; i += 256) {
        ((uint4*)row)[i] = z;
        ((uint4*)(row + (size_t)(P8W - 8) * NC))[i] = z;
      }
    }
  }
}

// ---------------- weight prep (fused): W[co][ci][3][3] f32 -> [cb*9+t][co][32] bf16 ----------------
__global__ void __launch_bounds__(256) wprep_kernel(const float* __restrict__ W1,
                                                    const float* __restrict__ W2,
                                                    uint16_t* __restrict__ d1,
                                                    uint16_t* __restrict__ d2) {
  int co = blockIdx.x;
  int which = blockIdx.y;
  const float* wsrc = which ? W2 : W1;
  uint16_t* dst = which ? d2 : d1;
  int cin = which ? NC : CATC;
  for (int ci = threadIdx.x; ci < cin; ci += 256) {
    const float* s = wsrc + ((size_t)co * cin + ci) * 9;
    int cb = ci >> 5, cil = ci & 31;
#pragma unroll
    for (int t = 0; t < 9; ++t)
      dst[(((size_t)(cb * 9 + t)) * 256 + co) * 32 + cil] = f2bf(s[t]);
  }
}

// ---------------- NCHW f32 -> padded NHWC bf16 (fcat sections + f1p8) ----------------
__global__ void __launch_bounds__(256) transpose_kernel(const float* __restrict__ f0,
                                                        const float* __restrict__ f1,
                                                        uint16_t* __restrict__ fcat,
                                                        uint16_t* __restrict__ f1p8) {
  __shared__ float tile[32][33];
  int tid = threadIdx.x;
  int tx = tid & 31, ty = tid >> 5;
  int xb = blockIdx.x;        // 0..4  (32 x each)
  int y = blockIdx.y;         // 0..95
  int z = blockIdx.z;         // b(2) * which(2) * cb(8)
  int b = z >> 4, which = (z >> 3) & 1, cb = z & 7;
  const float* src = which ? f1 : f0;
  int x0 = xb * 32;
#pragma unroll
  for (int j = 0; j < 4; ++j) {
    int c = cb * 32 + ty + j * 8;
    tile[ty + j * 8][tx] = src[((size_t)(b * NC + c) * NH + y) * NW + x0 + tx];
  }
  __syncthreads();
#pragma unroll
  for (int j = 0; j < 4; ++j) {
    int lx = ty + j * 8;
    int x = x0 + lx;
    int c = cb * 32 + tx;
    uint16_t v = f2bf(tile[tx][lx]);
    size_t base = ((size_t)(b * HP + y + 1) * WP + (x + 1)) * CATC;
    if (which == 0) {
      fcat[base + c] = v;
    } else {
      fcat[base + 512 + c] = v;
      f1p8[((size_t)(b * P8H + y + 8) * P8W + (x + 8)) * NC + c] = v;
    }
  }
}

// ---------------- correlation via MFMA band-GEMM: writes fcat channels 256..511 ----------------
__global__ void __launch_bounds__(256) corr_kernel(const uint16_t* __restrict__ fcat,
                                                   const uint16_t* __restrict__ f1p8,
                                                   uint16_t* __restrict__ fout) {
  int tid = threadIdx.x;
  int lane = tid & 63, w = tid >> 6;
  int lr = lane & 15, lk = lane >> 4;
  int lin = blockIdx.x;                       // 0..959
  int wid = (lin & 7) * 120 + (lin >> 3);     // XCD swizzle
  int y = wid % 96, xt = wid / 96;
  int b = blockIdx.y;
  int x0 = xt * 16;

  bf16x8 af[8];
  const uint16_t* abase = fcat + ((size_t)(b * HP + y + 1) * WP + (x0 + lr + 1)) * CATC + lk * 8;
#pragma unroll
  for (int kk = 0; kk < 8; ++kk) af[kk] = *(const bf16x8*)(abase + kk * 32);

  for (int g = 0; g < 4; ++g) {
    int pi = g * 4 + w;
    const uint16_t* bbase =
        f1p8 + ((size_t)(b * P8H + y + pi) * P8W + x0) * NC + lk * 8;
    bf16x8 bf0[8], bf1[8];
#pragma unroll
    for (int kk = 0; kk < 8; ++kk) {
      bf0[kk] = *(const bf16x8*)(bbase + (size_t)lr * NC + kk * 32);
      bf1[kk] = *(const bf16x8*)(bbase + (size_t)(16 + lr) * NC + kk * 32);
    }
    f32x4 acc0 = (f32x4){0.f, 0.f, 0.f, 0.f};
    f32x4 acc1 = (f32x4){0.f, 0.f, 0.f, 0.f};
#pragma unroll
    for (int kk = 0; kk < 8; ++kk) {
      acc0 = __builtin_amdgcn_mfma_f32_16x16x32_bf16(af[kk], bf0[kk], acc0, 0, 0, 0);
      acc1 = __builtin_amdgcn_mfma_f32_16x16x32_bf16(af[kk], bf1[kk], acc1, 0, 0, 0);
    }
    size_t orow = ((size_t)(b * HP + y + 1) * WP + (x0 + 1)) * CATC + 256 + (size_t)pi * 16;
#pragma unroll
    for (int j = 0; j < 4; ++j) {
      int xl = lk * 4 + j;
      int pj0 = lr - xl;
      if (pj0 >= 0) fout[orow + (size_t)xl * CATC + pj0] = f2bf(acc0[j]);
      int pj1 = 16 + lr - xl;
      if (pj1 < 16) fout[orow + (size_t)xl * CATC + pj1] = f2bf(acc1[j]);
    }
  }
}

// ---------------- conv1: halo-tile implicit GEMM ----------------
// 480 blocks (64 px: 16x x 4y), 4 waves; wave w owns co [w*64, w*64+64).
// Per cb (32 ch): 6x18-px halo in LDS (reg-staged, 2 buffers) -> 9 taps x 16 MFMA = 144
// MFMA per barrier. Weights stream global->reg, 3 buffers, 2-tap prefetch (wp linear in
// kt = cb*9+t). ds_reads contiguous per wave (lanes = consecutive x) -> conflict-free.
__global__ __launch_bounds__(256, 2) void conv1_kernel(const uint16_t* __restrict__ fcat,
                                                       const uint16_t* __restrict__ wp,
                                                       const float* __restrict__ bias,
                                                       uint16_t* __restrict__ hbuf) {
  constexpr int NCB = 24, NT = 216;
  __shared__ __align__(16) uint16_t As[2][6 * 18 * 32];  // 2 x 6912 B
  int tid = threadIdx.x;
  int w = tid >> 6, lane = tid & 63, lr = lane & 15, lk = lane >> 4;
  int orig = blockIdx.x;                    // 0..479
  int swz = (orig & 7) * 60 + (orig >> 3);  // XCD-bijective (480 % 8 == 0)
  int b = swz / 240, rem = swz % 240;
  int xt = rem / 24, yt = rem % 24;
  int x0 = xt * 16, y0 = yt * 4;

  // halo staging map: 432 16B-units over [6 rows][18 x][4 q]
  int u0 = tid;
  int u1 = tid + 256 < 432 ? tid + 256 : 431;  // clamped duplicate (benign)
  int yh0 = u0 / 72, r0 = u0 - yh0 * 72, xh0 = r0 >> 2, q0 = r0 & 3;
  int yh1 = u1 / 72, r1 = u1 - yh1 * 72, xh1 = r1 >> 2, q1 = r1 & 3;
  const uint16_t* gbase = fcat + ((size_t)(b * HP + y0) * WP + x0) * CATC;
  const uint16_t* gp0 = gbase + (yh0 * WP + xh0) * CATC + q0 * 8;
  const uint16_t* gp1 = gbase + (yh1 * WP + xh1) * CATC + q1 * 8;
  int ld0 = (yh0 * 18 + xh0) * 32 + q0 * 8;
  int ld1 = (yh1 * 18 + xh1) * 32 + q1 * 8;
  uint16_t* wA0a = &As[0][0] + ld0;
  uint16_t* wA0b = &As[0][0] + ld1;
  uint16_t* wA1a = &As[1][0] + ld0;
  uint16_t* wA1b = &As[1][0] + ld1;
  const uint16_t* lA0 = &As[0][0] + lr * 32 + lk * 8;  // + (m+dy)*576 + dx*32 (imm)
  const uint16_t* lA1 = &As[1][0] + lr * 32 + lk * 8;
  const uint16_t* wlane = wp + ((size_t)(w * 64 + lr)) * 32 + lk * 8;

  float bv[4];
#pragma unroll
  for (int n = 0; n < 4; ++n) bv[n] = bias[w * 64 + n * 16 + lr];

  f32x4 acc[4][4];
#pragma unroll
  for (int m = 0; m < 4; ++m)
#pragma unroll
    for (int n = 0; n < 4; ++n) acc[m][n] = (f32x4){0.f, 0.f, 0.f, 0.f};

  bf16x8 bx[3][4];

#define LOADB1(slot, kt)                                                         \
  {                                                                              \
    const uint16_t* p_ = wlane + (size_t)(kt)*8192;                              \
    _Pragma("unroll") for (int n_ = 0; n_ < 4; ++n_) bx[slot][n_] =              \
        *(const bf16x8*)(p_ + n_ * 512);                                         \
  }

#define TAP1(base, cb9, t)                                                             \
  {                                                                                    \
    bf16x8 af[4];                                                                      \
    _Pragma("unroll") for (int m_ = 0; m_ < 4; ++m_) af[m_] =                          \
        *(const bf16x8*)((base) + ((t) / 3) * 576 + ((t) % 3) * 32 + m_ * 576);        \
    int ktn_ = (cb9) + (t) + 2;                                                        \
    ktn_ = ktn_ < NT ? ktn_ : NT - 1;                                                  \
    LOADB1(((t) + 2) % 3, ktn_);                                                       \
    _Pragma("unroll") for (int m_ = 0; m_ < 4; ++m_)                                   \
        _Pragma("unroll") for (int n_ = 0; n_ < 4; ++n_) acc[m_][n_] =                 \
            __builtin_amdgcn_mfma_f32_16x16x32_bf16(af[m_], bx[(t) % 3][n_],           \
                                                    acc[m_][n_], 0, 0, 0);             \
  }

  // prologue: halo(cb0) -> As[0]; halo(cb1) -> regs; weights kt=0,1
  uint4 xrA0 = *(const uint4*)gp0;
  uint4 xrA1 = *(const uint4*)gp1;
  *(uint4*)wA0a = xrA0;
  *(uint4*)wA0b = xrA1;
  xrA0 = *(const uint4*)(gp0 + 32);
  xrA1 = *(const uint4*)(gp1 + 32);
  uint4 xrB0, xrB1;
  LOADB1(0, 0);
  LOADB1(1, 1);
  asm volatile("s_waitcnt lgkmcnt(0)" ::: "memory");
  __builtin_amdgcn_s_barrier();

  for (int cbp = 0; cbp < NCB; cbp += 2) {
    int cb9a = cbp * 9;
    {  // read As[0] (cb=cbp); write halo(cbp+1) -> As[1]; load halo(cbp+2) -> xrB
      *(uint4*)wA1a = xrA0;
      *(uint4*)wA1b = xrA1;
      int cbl = cbp + 2 < NCB ? cbp + 2 : NCB - 1;
      xrB0 = *(const uint4*)(gp0 + cbl * 32);
      xrB1 = *(const uint4*)(gp1 + cbl * 32);
#pragma unroll
      for (int t = 0; t < 9; ++t) TAP1(lA0, cb9a, t);
      asm volatile("s_waitcnt lgkmcnt(0)" ::: "memory");
      __builtin_amdgcn_s_barrier();
    }
    {  // read As[1] (cb=cbp+1); write halo(cbp+2) -> As[0]; load halo(cbp+3) -> xrA
      *(uint4*)wA0a = xrB0;
      *(uint4*)wA0b = xrB1;
      int cbl = cbp + 3 < NCB ? cbp + 3 : NCB - 1;
      xrA0 = *(const uint4*)(gp0 + cbl * 32);
      xrA1 = *(const uint4*)(gp1 + cbl * 32);
      int cb9b = cb9a + 9;
#pragma unroll
      for (int t = 0; t < 9; ++t) TAP1(lA1, cb9b, t);
      asm volatile("s_waitcnt lgkmcnt(0)" ::: "memory");
      __builtin_amdgcn_s_barrier();
    }
  }

  // epilogue: D row = x (lk*4+j), col = co-local (lr); frag m = y, frag n = co-block
#pragma unroll
  for (int m = 0; m < 4; ++m) {
#pragma unroll
    for (int j = 0; j < 4; ++j) {
      int x = lk * 4 + j;
      size_t base = ((size_t)(b * HP + y0 + m + 1) * WP + (x0 + x + 1)) * NC;
#pragma unroll
      for (int n = 0; n < 4; ++n) {
        float v = acc[m][n][j] + bv[n];
        v = v > 0.f ? v : 0.f;
        hbuf[base + w * 64 + n * 16 + lr] = f2bf(v);
      }
    }
  }
#undef LOADB1
#undef TAP1
}

// ---------------- conv2: same halo template, operands swapped ----------------
// A = weights (co rows, streamed regs), B = activation halo (LDS). D row = co, col = x
// -> coalesced f32 NCHW epilogue with + bias + f1.
__global__ __launch_bounds__(256, 2) void conv2_kernel(const uint16_t* __restrict__ hbuf,
                                                       const uint16_t* __restrict__ wp,
                                                       const float* __restrict__ bias,
                                                       const float* __restrict__ f1,
                                                       float* __restrict__ out) {
  constexpr int NCB = 8, NT = 72;
  __shared__ __align__(16) uint16_t Xs[2][6 * 18 * 32];
  int tid = threadIdx.x;
  int w = tid >> 6, lane = tid & 63, lr = lane & 15, lk = lane >> 4;
  int orig = blockIdx.x;
  int swz = (orig & 7) * 60 + (orig >> 3);
  int b = swz / 240, rem = swz % 240;
  int xt = rem / 24, yt = rem % 24;
  int x0 = xt * 16, y0 = yt * 4;

  int u0 = tid;
  int u1 = tid + 256 < 432 ? tid + 256 : 431;
  int yh0 = u0 / 72, r0 = u0 - yh0 * 72, xh0 = r0 >> 2, q0 = r0 & 3;
  int yh1 = u1 / 72, r1 = u1 - yh1 * 72, xh1 = r1 >> 2, q1 = r1 & 3;
  const uint16_t* gbase = hbuf + ((size_t)(b * HP + y0) * WP + x0) * NC;
  const uint16_t* gp0 = gbase + (yh0 * WP + xh0) * NC + q0 * 8;
  const uint16_t* gp1 = gbase + (yh1 * WP + xh1) * NC + q1 * 8;
  int ld0 = (yh0 * 18 + xh0) * 32 + q0 * 8;
  int ld1 = (yh1 * 18 + xh1) * 32 + q1 * 8;
  uint16_t* wX0a = &Xs[0][0] + ld0;
  uint16_t* wX0b = &Xs[0][0] + ld1;
  uint16_t* wX1a = &Xs[1][0] + ld0;
  uint16_t* wX1b = &Xs[1][0] + ld1;
  const uint16_t* lX0 = &Xs[0][0] + lr * 32 + lk * 8;
  const uint16_t* lX1 = &Xs[1][0] + lr * 32 + lk * 8;
  const uint16_t* wlane = wp + ((size_t)(w * 64 + lr)) * 32 + lk * 8;

  float bv[4][4];
#pragma unroll
  for (int m = 0; m < 4; ++m)
#pragma unroll
    for (int j = 0; j < 4; ++j) bv[m][j] = bias[w * 64 + m * 16 + lk * 4 + j];

  f32x4 acc[4][4];
#pragma unroll
  for (int m = 0; m < 4; ++m)
#pragma unroll
    for (int n = 0; n < 4; ++n) acc[m][n] = (f32x4){0.f, 0.f, 0.f, 0.f};

  bf16x8 wr[3][4];

#define LOADW2(slot, kt)                                                         \
  {                                                                              \
    const uint16_t* p_ = wlane + (size_t)(kt)*8192;                              \
    _Pragma("unroll") for (int m_ = 0; m_ < 4; ++m_) wr[slot][m_] =              \
        *(const bf16x8*)(p_ + m_ * 512);                                         \
  }

#define TAP2(base, cb9, t)                                                             \
  {                                                                                    \
    bf16x8 bxf[4];                                                                     \
    _Pragma("unroll") for (int n_ = 0; n_ < 4; ++n_) bxf[n_] =                         \
        *(const bf16x8*)((base) + ((t) / 3) * 576 + ((t) % 3) * 32 + n_ * 576);        \
    int ktn_ = (cb9) + (t) + 2;                                                        \
    ktn_ = ktn_ < NT ? ktn_ : NT - 1;                                                  \
    LOADW2(((t) + 2) % 3, ktn_);                                                       \
    _Pragma("unroll") for (int m_ = 0; m_ < 4; ++m_)                                   \
        _Pragma("unroll") for (int n_ = 0; n_ < 4; ++n_) acc[m_][n_] =                 \
            __builtin_amdgcn_mfma_f32_16x16x32_bf16(wr[(t) % 3][m_], bxf[n_],          \
                                                    acc[m_][n_], 0, 0, 0);             \
  }

  uint4 xrA0 = *(const uint4*)gp0;
  uint4 xrA1 = *(const uint4*)gp1;
  *(uint4*)wX0a = xrA0;
  *(uint4*)wX0b = xrA1;
  xrA0 = *(const uint4*)(gp0 + 32);
  xrA1 = *(const uint4*)(gp1 + 32);
  uint4 xrB0, xrB1;
  LOADW2(0, 0);
  LOADW2(1, 1);
  asm volatile("s_waitcnt lgkmcnt(0)" ::: "memory");
  __builtin_amdgcn_s_barrier();

  for (int cbp = 0; cbp < NCB; cbp += 2) {
    int cb9a = cbp * 9;
    {
      *(uint4*)wX1a = xrA0;
      *(uint4*)wX1b = xrA1;
      int cbl = cbp + 2 < NCB ? cbp + 2 : NCB - 1;
      xrB0 = *(const uint4*)(gp0 + cbl * 32);
      xrB1 = *(const uint4*)(gp1 + cbl * 32);
#pragma unroll
      for (int t = 0; t < 9; ++t) TAP2(lX0, cb9a, t);
      asm volatile("s_waitcnt lgkmcnt(0)" ::: "memory");
      __builtin_amdgcn_s_barrier();
    }
    {
      *(uint4*)wX0a = xrB0;
      *(uint4*)wX0b = xrB1;
      int cbl = cbp + 3 < NCB ? cbp + 3 : NCB - 1;
      xrA0 = *(const uint4*)(gp0 + cbl * 32);
      xrA1 = *(const uint4*)(gp1 + cbl * 32);
      int cb9b = cb9a + 9;
#pragma unroll
      for (int t = 0; t < 9; ++t) TAP2(lX1, cb9b, t);
      asm volatile("s_waitcnt lgkmcnt(0)" ::: "memory");
      __builtin_amdgcn_s_barrier();
    }
  }

  // epilogue: D row = co-local (lk*4+j) in frag m, col = x (lr); frag n = y
#pragma unroll
  for (int m = 0; m < 4; ++m) {
#pragma unroll
    for (int j = 0; j < 4; ++j) {
      int co = w * 64 + m * 16 + lk * 4 + j;
#pragma unroll
      for (int n = 0; n < 4; ++n) {
        size_t idx = ((size_t)(b * NC + co) * NH + (y0 + n)) * NW + x0 + lr;
        out[idx] = acc[m][n][j] + bv[m][j] + f1[idx];
      }
    }
  }
#undef LOADW2
#undef TAP2
}

extern "C" void kernel_launch(void* const* d_in, const int* in_sizes, int n_in,
                              void* d_out, int out_size, void* d_ws, size_t ws_size,
                              hipStream_t stream) {
  (void)in_sizes; (void)n_in; (void)out_size; (void)ws_size;
  const float* f0 = (const float*)d_in[0];
  const float* f1 = (const float*)d_in[1];
  const float* W1 = (const float*)d_in[2];
  const float* b1 = (const float*)d_in[3];
  const float* W2 = (const float*)d_in[4];
  const float* b2 = (const float*)d_in[5];
  float* out = (float*)d_out;

  char* ws = (char*)d_ws;
  size_t s_fcat = (size_t)NB * HP * WP * CATC * 2;  // 48.8 MB
  size_t s_f1p8 = (size_t)NB * P8H * P8W * NC * 2;  // 20.2 MB
  size_t s_h = (size_t)NB * HP * WP * NC * 2;       // 16.3 MB
  size_t s_bp1 = (size_t)216 * 256 * 32 * 2;        // 3.5 MB
  uint16_t* fcat = (uint16_t*)ws;
  uint16_t* f1p8 = (uint16_t*)(ws + s_fcat);
  uint16_t* hbuf = (uint16_t*)(ws + s_fcat + s_f1p8);
  uint16_t* bp1 = (uint16_t*)(ws + s_fcat + s_f1p8 + s_h);
  uint16_t* bp2 = (uint16_t*)(ws + s_fcat + s_f1p8 + s_h + s_bp1);

  bzero_kernel<<<dim3(224, 3), 256, 0, stream>>>(fcat, f1p8, hbuf);
  wprep_kernel<<<dim3(256, 2), 256, 0, stream>>>(W1, W2, bp1, bp2);
  transpose_kernel<<<dim3(5, 96, 32), 256, 0, stream>>>(f0, f1, fcat, f1p8);
  corr_kernel<<<dim3(960, 2), 256, 0, stream>>>(fcat, f1p8, fcat);
  conv1_kernel<<<480, 256, 0, stream>>>(fcat, bp1, b1, hbuf);
  conv2_kernel<<<480, 256, 0, stream>>>(hbuf, bp2, b2, f1, out);
}